// Round 5
// baseline (1306.042 us; speedup 1.0000x reference)
//
#include <hip/hip_runtime.h>
#include <math.h>

#define B_ROWS 32768
#define D_DIM  512
#define K_EMB  8192
#define EPS 0.10f
#define RSPLIT 8

typedef __attribute__((ext_vector_type(4))) float f32x4;
typedef __attribute__((ext_vector_type(8))) short bf16x8;

#define GLL16(gp, lp)                                                          \
  __builtin_amdgcn_global_load_lds(                                            \
      (const __attribute__((address_space(1))) void*)(gp),                     \
      (__attribute__((address_space(3))) void*)(lp), 16, 0, 0)

// ---------------------------------------------------------------------------
// fp32 -> bf16 hi + residual lo (RNE), fused with row squared-norm.
// One kernel for both z (blocks < 8192) and W (blocks >= 8192).
// ---------------------------------------------------------------------------
__device__ __forceinline__ unsigned bf_rne(float x) {
  unsigned u = __float_as_uint(x);
  return (u + 0x7fffu + ((u >> 16) & 1u)) >> 16;
}

__global__ __launch_bounds__(256) void prep_all_kernel(
    const float* __restrict__ z, const float* __restrict__ W,
    short* __restrict__ zhi, short* __restrict__ zlo,
    short* __restrict__ whi, short* __restrict__ wlo,
    float* __restrict__ zz, float* __restrict__ wsq) {
  const int wave = threadIdx.x >> 6;
  const int lane = threadIdx.x & 63;
  const float* X; short* hi; short* lo; float* sq; int row;
  if (blockIdx.x < B_ROWS / 4) {
    row = blockIdx.x * 4 + wave;
    X = z; hi = zhi; lo = zlo; sq = zz;
  } else {
    row = (blockIdx.x - B_ROWS / 4) * 4 + wave;
    X = W; hi = whi; lo = wlo; sq = wsq;
  }
  const float* xr = X + (size_t)row * D_DIM;
  float4 x0 = ((const float4*)xr)[lane * 2];
  float4 x1 = ((const float4*)xr)[lane * 2 + 1];
  float xs[8] = {x0.x, x0.y, x0.z, x0.w, x1.x, x1.y, x1.z, x1.w};
  union { short s[8]; int4 v; } H, L;
  float ssum = 0.f;
  #pragma unroll
  for (int j = 0; j < 8; ++j) {
    unsigned rh = bf_rne(xs[j]);
    H.s[j] = (short)rh;
    float h = __uint_as_float(rh << 16);
    L.s[j] = (short)bf_rne(xs[j] - h);
    ssum += xs[j] * xs[j];
  }
  *(int4*)(hi + (size_t)row * D_DIM + lane * 8) = H.v;
  *(int4*)(lo + (size_t)row * D_DIM + lane * 8) = L.v;
  #pragma unroll
  for (int o = 32; o > 0; o >>= 1) ssum += __shfl_xor(ssum, o, 64);
  if (lane == 0) sq[row] = ssum;
}

// ---------------------------------------------------------------------------
// Stage 1: persistent-z hi*hi top-2 argmin, BARRIER-FREE K-loop.
// 256 blocks x 512 threads (1 block/CU, 128 KB LDS). z-hi tile [dc64][row128][8]
// loaded once via global_load_lds. B-fragments loaded global->VGPR directly
// (W is L2/L3-resident). 8 waves as 2(row)x4(code); wave tile 64x64.
// Tail: reduce 64 candidates/row, then commit (top2 gap >= EPS) or flag.
// ---------------------------------------------------------------------------
__global__ __launch_bounds__(512) void stage1_kernel(
    const short* __restrict__ zhi, const short* __restrict__ whi,
    const float* __restrict__ wsq, int* __restrict__ idx,
    float* __restrict__ out_idx_f, int* __restrict__ hist,
    unsigned long long* __restrict__ packed, int* __restrict__ cnt,
    int* __restrict__ list) {
  __shared__ short Zt[65536];          // 128 KB: [dc 0..63][row 0..127][8]
  float* rv1 = (float*)Zt;             // post-loop overlay: 32 KB
  int*   ri1 = (int*)(Zt + 16384);     // +32 KB
  float* rv2 = (float*)(Zt + 32768);   // +32 KB

  const int tid = threadIdx.x;
  const int lane = tid & 63;
  const int wave = tid >> 6;
  const int wm = wave >> 2;            // 0..1 row half
  const int wn = wave & 3;             // 0..3 code quarter
  const int l15 = lane & 15, l4 = lane >> 4;
  const int row0 = blockIdx.x * 128;

  #pragma unroll
  for (int j = 0; j < 16; ++j) {
    const int slot = j * 512 + tid;
    const int r = slot & 127, dc = slot >> 7;
    GLL16(zhi + (size_t)(row0 + r) * D_DIM + dc * 8, Zt + (size_t)slot * 8);
  }
  __syncthreads();   // the ONLY barrier before the tail

  float v1[16], v2[16];
  int   i1[16];
  #pragma unroll
  for (int s = 0; s < 16; ++s) { v1[s] = INFINITY; v2[s] = INFINITY; i1[s] = 0x7fffffff; }

  // lane-fixed base into W: code (wn*64 + l15), dim offset l4*8
  const short* wb = whi + (size_t)(wn * 64 + l15) * D_DIM + l4 * 8;

  for (int kt = 0; kt < K_EMB; kt += 256) {
    f32x4 acc[4][4];
    #pragma unroll
    for (int rb = 0; rb < 4; ++rb)
      #pragma unroll
      for (int cb = 0; cb < 4; ++cb) acc[rb][cb] = (f32x4)0.f;

    #pragma unroll 4
    for (int d0 = 0; d0 < D_DIM; d0 += 32) {
      bf16x8 a[4], b[4];
      const int dcb = d0 >> 3;
      #pragma unroll
      for (int cb = 0; cb < 4; ++cb)
        b[cb] = *(const bf16x8*)(wb + (size_t)(kt + cb * 16) * D_DIM + d0);
      #pragma unroll
      for (int rb = 0; rb < 4; ++rb)
        a[rb] = *(const bf16x8*)&Zt[((dcb + l4) * 128 + wm * 64 + rb * 16 + l15) * 8];
      #pragma unroll
      for (int rb = 0; rb < 4; ++rb)
        #pragma unroll
        for (int cb = 0; cb < 4; ++cb)
          acc[rb][cb] = __builtin_amdgcn_mfma_f32_16x16x32_bf16(
              a[rb], b[cb], acc[rb][cb], 0, 0, 0);
    }

    // proxy distance wsq[c] - 2*dot (row-constant zz dropped: ordering safe)
    #pragma unroll
    for (int cb = 0; cb < 4; ++cb) {
      const int col = kt + wn * 64 + cb * 16 + l15;
      const float wv = wsq[col];
      #pragma unroll
      for (int rb = 0; rb < 4; ++rb) {
        f32x4 a = acc[rb][cb];
        #pragma unroll
        for (int rg = 0; rg < 4; ++rg) {
          const float dist = wv - 2.0f * a[rg];
          const int s = rb * 4 + rg;
          if (dist < v1[s] || (dist == v1[s] && col < i1[s])) {
            v2[s] = v1[s]; v1[s] = dist; i1[s] = col;
          } else {
            v2[s] = fminf(v2[s], dist);
          }
        }
      }
    }
  }

  __syncthreads();  // all waves done with Zt -> overlay reduction arrays
  #pragma unroll
  for (int rb = 0; rb < 4; ++rb)
    #pragma unroll
    for (int rg = 0; rg < 4; ++rg) {
      const int s = rb * 4 + rg;
      const int R = wm * 64 + rb * 16 + l4 * 4 + rg;
      const int c = wn * 16 + l15;
      rv1[R * 64 + c] = v1[s];
      ri1[R * 64 + c] = i1[s];
      rv2[R * 64 + c] = v2[s];
    }
  __syncthreads();

  if (tid < 128) {
    float V1 = INFINITY, V2 = INFINITY;
    int I1 = 0x7fffffff;
    #pragma unroll 8
    for (int t = 0; t < 64; ++t) {
      const float a1 = rv1[tid * 64 + t];
      const int ai = ri1[tid * 64 + t];
      const float a2 = rv2[tid * 64 + t];
      if (a1 < V1 || (a1 == V1 && ai < I1)) {
        V2 = fminf(V1, a2); V1 = a1; I1 = ai;
      } else {
        V2 = fminf(V2, a1);
      }
    }
    const int row = row0 + tid;
    if (V2 - V1 >= EPS) {
      idx[row] = I1;
      out_idx_f[row] = (float)I1;
      atomicAdd(&hist[I1], 1);
    } else {
      packed[row] = 0xffffffffffffffffULL;
      const int p = atomicAdd(cnt, 1);
      list[p] = row;
    }
  }
}

// ---------------------------------------------------------------------------
// Refine: exact 3-pass (hh+hl+lh) argmin over ALL codes for flagged rows.
// Barrier-free K-loop; 64 gathered z rows (hi+lo) staged to LDS via ds_write.
// Split-K=8 across blocks; merged via packed atomicMin (val, then lowest idx).
// ---------------------------------------------------------------------------
__global__ __launch_bounds__(512) void refine_kernel(
    const short* __restrict__ zhi, const short* __restrict__ zlo,
    const short* __restrict__ whi, const short* __restrict__ wlo,
    const float* __restrict__ zz, const float* __restrict__ wsq,
    const int* __restrict__ cnt, const int* __restrict__ list,
    unsigned long long* __restrict__ packed) {
  __shared__ short Zh[32768];          // 64 KB: [dc64][row64][8]
  __shared__ short Zl[32768];          // 64 KB
  float* rv = (float*)Zh;              // post-loop overlay 16 KB
  int*   ri = (int*)(Zh + 8192);       // +16 KB

  const int n = *cnt;
  const int rt = blockIdx.x >> 3;
  const int ks = blockIdx.x & 7;
  if (rt * 64 >= n) return;
  const int k0 = ks * (K_EMB / RSPLIT);   // 1024 codes per split

  const int tid = threadIdx.x;
  const int lane = tid & 63;
  const int wave = tid >> 6;
  const int wm = wave >> 2;            // 0..1 : 32 rows each
  const int wn = wave & 3;             // 0..3 : 64 codes each of 256-tile
  const int l15 = lane & 15, l4 = lane >> 4;

  // gather 64 flagged rows (hi+lo) into LDS
  #pragma unroll
  for (int j = 0; j < 8; ++j) {
    const int slot = j * 512 + tid;    // 4096 slots
    const int r = slot & 63, dc = slot >> 6;
    const int gr = list[min(rt * 64 + r, n - 1)];
    *(int4*)&Zh[(size_t)slot * 8] = *(const int4*)(zhi + (size_t)gr * D_DIM + dc * 8);
    *(int4*)&Zl[(size_t)slot * 8] = *(const int4*)(zlo + (size_t)gr * D_DIM + dc * 8);
  }

  float zzr[8];
  #pragma unroll
  for (int rb = 0; rb < 2; ++rb)
    #pragma unroll
    for (int rg = 0; rg < 4; ++rg) {
      const int R = wm * 32 + rb * 16 + l4 * 4 + rg;
      zzr[rb * 4 + rg] = zz[list[min(rt * 64 + R, n - 1)]];
    }
  __syncthreads();

  float best[8];
  int   bidx[8];
  #pragma unroll
  for (int s = 0; s < 8; ++s) { best[s] = INFINITY; bidx[s] = 0x7fffffff; }

  const short* wbh = whi + (size_t)(k0 + wn * 64 + l15) * D_DIM + l4 * 8;
  const short* wbl = wlo + (size_t)(k0 + wn * 64 + l15) * D_DIM + l4 * 8;

  for (int kt = 0; kt < K_EMB / RSPLIT; kt += 256) {
    f32x4 acc[2][4];
    #pragma unroll
    for (int rb = 0; rb < 2; ++rb)
      #pragma unroll
      for (int cb = 0; cb < 4; ++cb) acc[rb][cb] = (f32x4)0.f;

    #pragma unroll 4
    for (int d0 = 0; d0 < D_DIM; d0 += 32) {
      bf16x8 ah[2], al[2], bh[4], bl[4];
      const int dcb = d0 >> 3;
      #pragma unroll
      for (int cb = 0; cb < 4; ++cb) {
        bh[cb] = *(const bf16x8*)(wbh + (size_t)(kt + cb * 16) * D_DIM + d0);
        bl[cb] = *(const bf16x8*)(wbl + (size_t)(kt + cb * 16) * D_DIM + d0);
      }
      #pragma unroll
      for (int rb = 0; rb < 2; ++rb) {
        const int m = wm * 32 + rb * 16 + l15;
        ah[rb] = *(const bf16x8*)&Zh[((dcb + l4) * 64 + m) * 8];
        al[rb] = *(const bf16x8*)&Zl[((dcb + l4) * 64 + m) * 8];
      }
      #pragma unroll
      for (int rb = 0; rb < 2; ++rb)
        #pragma unroll
        for (int cb = 0; cb < 4; ++cb) {
          acc[rb][cb] = __builtin_amdgcn_mfma_f32_16x16x32_bf16(
              ah[rb], bh[cb], acc[rb][cb], 0, 0, 0);
          acc[rb][cb] = __builtin_amdgcn_mfma_f32_16x16x32_bf16(
              ah[rb], bl[cb], acc[rb][cb], 0, 0, 0);
          acc[rb][cb] = __builtin_amdgcn_mfma_f32_16x16x32_bf16(
              al[rb], bh[cb], acc[rb][cb], 0, 0, 0);
        }
    }

    #pragma unroll
    for (int cb = 0; cb < 4; ++cb) {
      const int col = k0 + kt + wn * 64 + cb * 16 + l15;
      const float wv = wsq[col];
      #pragma unroll
      for (int rb = 0; rb < 2; ++rb) {
        f32x4 a = acc[rb][cb];
        #pragma unroll
        for (int rg = 0; rg < 4; ++rg) {
          const float dist = (zzr[rb * 4 + rg] + wv) - 2.0f * a[rg];
          const int s = rb * 4 + rg;
          if (dist < best[s]) { best[s] = dist; bidx[s] = col; }
        }
      }
    }
  }

  __syncthreads();
  #pragma unroll
  for (int rb = 0; rb < 2; ++rb)
    #pragma unroll
    for (int rg = 0; rg < 4; ++rg) {
      const int s = rb * 4 + rg;
      const int R = wm * 32 + rb * 16 + l4 * 4 + rg;
      rv[R * 64 + wn * 16 + l15] = best[s];
      ri[R * 64 + wn * 16 + l15] = bidx[s];
    }
  __syncthreads();

  if (tid < 64 && rt * 64 + tid < n) {
    float bv = INFINITY;
    int bi = 0x7fffffff;
    #pragma unroll 8
    for (int t = 0; t < 64; ++t) {
      const float v = rv[tid * 64 + t];
      const int ix = ri[tid * 64 + t];
      if (v < bv || (v == bv && ix < bi)) { bv = v; bi = ix; }
    }
    const int row = list[rt * 64 + tid];
    const unsigned long long pk =
        ((unsigned long long)__float_as_uint(bv) << 32) | (unsigned)bi;
    atomicMin(&packed[row], pk);
  }
}

// ---------------------------------------------------------------------------
__global__ __launch_bounds__(256) void final_merge_kernel(
    const int* __restrict__ cnt, const int* __restrict__ list,
    const unsigned long long* __restrict__ packed, int* __restrict__ idx,
    float* __restrict__ out_idx_f, int* __restrict__ hist) {
  const int t = blockIdx.x * 256 + threadIdx.x;
  if (t >= *cnt) return;
  const int row = list[t];
  const int bi = (int)(packed[row] & 0xffffffffULL);
  idx[row] = bi;
  out_idx_f[row] = (float)bi;
  atomicAdd(&hist[bi], 1);
}

// ---------------------------------------------------------------------------
__global__ __launch_bounds__(256) void gather_kernel(
    const float* __restrict__ z, const float* __restrict__ W,
    const int* __restrict__ idx, float* __restrict__ out,
    double* __restrict__ mse_sum) {
  const int wave = threadIdx.x >> 6;
  const int lane = threadIdx.x & 63;
  const int row = blockIdx.x * 4 + wave;
  const int k = idx[row];
  const float* zr = z + (size_t)row * D_DIM;
  const float* wr = W + (size_t)k * D_DIM;
  float* outr = out + (size_t)row * D_DIM;
  float s = 0.f;
  #pragma unroll
  for (int h = 0; h < 2; ++h) {
    const int c = h * 256 + lane * 4;
    float4 zv = *(const float4*)(zr + c);
    float4 qv = *(const float4*)(wr + c);
    float4 st;
    st.x = zv.x + (qv.x - zv.x);
    st.y = zv.y + (qv.y - zv.y);
    st.z = zv.z + (qv.z - zv.z);
    st.w = zv.w + (qv.w - zv.w);
    float dx = zv.x - qv.x, dy = zv.y - qv.y, dz = zv.z - qv.z, dw = zv.w - qv.w;
    s += dx * dx + dy * dy + dz * dz + dw * dw;
    *(float4*)(outr + c) = st;
  }
  #pragma unroll
  for (int o = 32; o > 0; o >>= 1) s += __shfl_xor(s, o, 64);
  if (lane == 0) atomicAdd(mse_sum, (double)s);
}

// ---------------------------------------------------------------------------
__global__ __launch_bounds__(256) void loss_kernel(
    const int* __restrict__ hist, const double* __restrict__ mse_sum,
    float* __restrict__ out_loss) {
  __shared__ float ls[4];
  const int tid = threadIdx.x;
  float e = 0.f;
  for (int b = tid; b < K_EMB; b += 256) {
    float p = (float)hist[b] * (1.0f / 32768.0f);
    e += p * logf(p + 1e-10f);
  }
  #pragma unroll
  for (int o = 32; o > 0; o >>= 1) e += __shfl_xor(e, o, 64);
  if ((tid & 63) == 0) ls[tid >> 6] = e;
  __syncthreads();
  if (tid == 0) {
    float entropy = -(ls[0] + ls[1] + ls[2] + ls[3]);
    float mse = (float)(*mse_sum / 16777216.0);
    float entropy_loss = 1.0f - entropy / logf(8192.0f);
    out_loss[0] = mse + 0.25f * mse + 0.1f * entropy_loss;
  }
}

// ---------------------------------------------------------------------------
extern "C" void kernel_launch(void* const* d_in, const int* in_sizes, int n_in,
                              void* d_out, int out_size, void* d_ws, size_t ws_size,
                              hipStream_t stream) {
  const float* z = (const float*)d_in[0];  // [32768,512]
  const float* W = (const float*)d_in[1];  // [8192,512]
  float* out = (float*)d_out;              // [B*D] st | [1] loss | [B] indices

  char* ws = (char*)d_ws;
  double* mse_sum = (double*)ws;                           // @0
  int*    cnt     = (int*)(ws + 8);                        // @8
  int*    hist    = (int*)(ws + 4096);                     // 32 KB
  unsigned long long* packed = (unsigned long long*)(ws + 65536);  // 256 KB
  float*  zz   = (float*)(ws + 327680);                    // 128 KB
  float*  wsq  = (float*)(ws + 458752);                    // 32 KB
  int*    idx  = (int*)(ws + 491520);                      // 128 KB
  int*    list = (int*)(ws + 622592);                      // 128 KB
  short*  zhi  = (short*)(ws + 4194304);                   // 32 MB
  short*  zlo  = (short*)(ws + 37748736);                  // 32 MB
  short*  whi  = (short*)(ws + 71303168);                  // 8 MB
  short*  wlo  = (short*)(ws + 79691776);                  // 8 MB (ends 84 MB)

  hipMemsetAsync(d_ws, 0, 36864, stream);  // mse_sum + cnt + hist

  prep_all_kernel<<<B_ROWS / 4 + K_EMB / 4, 256, 0, stream>>>(
      z, W, zhi, zlo, whi, wlo, zz, wsq);

  stage1_kernel<<<B_ROWS / 128, 512, 0, stream>>>(
      zhi, whi, wsq, idx, out + (size_t)B_ROWS * D_DIM + 1, hist,
      packed, cnt, list);

  refine_kernel<<<(B_ROWS / 64) * RSPLIT, 512, 0, stream>>>(
      zhi, zlo, whi, wlo, zz, wsq, cnt, list, packed);

  final_merge_kernel<<<B_ROWS / 256, 256, 0, stream>>>(
      cnt, list, packed, idx, out + (size_t)B_ROWS * D_DIM + 1, hist);

  gather_kernel<<<B_ROWS / 4, 256, 0, stream>>>(z, W, idx, out, mse_sum);

  loss_kernel<<<1, 256, 0, stream>>>(hist, mse_sum,
                                     out + (size_t)B_ROWS * D_DIM);
}